// Round 2
// baseline (966.681 us; speedup 1.0000x reference)
//
#include <hip/hip_runtime.h>

#define DEVFN __device__ __forceinline__

typedef float f32x4 __attribute__((ext_vector_type(4)));
typedef short bf16x8 __attribute__((ext_vector_type(8)));

constexpr int S = 4;
constexpr int T = 23;        // OUT_LEN - 1
constexpr int L = 24;
constexpr int BATCH = 16;
constexpr int H = 512;
constexpr int E = 512;
constexpr int V = 32000;
constexpr int G3 = 1536;     // 3*H
constexpr int KX = 1024;     // E+H
constexpr int F = 1536;      // E+2H
constexpr int MROWS = S * T * BATCH; // 1472
constexpr int MPAD = 1536;

DEVFN float b2f(unsigned short h) {
    union { unsigned int u; float f; } c; c.u = ((unsigned int)h) << 16; return c.f;
}
DEVFN unsigned short f2b(float f) {
    union { float f; unsigned int u; } c; c.f = f;
    unsigned int u = c.u;
    return (unsigned short)((u + 0x7FFFu + ((u >> 16) & 1u)) >> 16);
}
DEVFN float sigmoidf_(float x) { return 1.0f / (1.0f + __expf(-x)); }
DEVFN float tanh_fast(float x) { return 1.0f - 2.0f / (__expf(2.0f * x) + 1.0f); }

DEVFN f32x4 mfma16(bf16x8 a, bf16x8 b, f32x4 c) {
    return __builtin_amdgcn_mfma_f32_16x16x32_bf16(a, b, c, 0, 0, 0);
}
DEVFN void gld16(const unsigned short* g, unsigned short* l) {
    __builtin_amdgcn_global_load_lds((const __attribute__((address_space(1))) void*)g,
                                     (__attribute__((address_space(3))) void*)l, 16, 0, 0);
}
DEVFN bf16x8 ldb8(const unsigned short* p) { return *(const bf16x8*)p; }

// ---------------------------------------------------------------------------
// fp32 -> bf16 bulk convert (round-to-nearest-even). n4 = n/4.
// ---------------------------------------------------------------------------
__global__ void f32_to_bf16(const float* __restrict__ src,
                            unsigned short* __restrict__ dst, int n4)
{
    const int i = blockIdx.x * blockDim.x + threadIdx.x;
    if (i >= n4) return;
    const float4 v = ((const float4*)src)[i];
    ushort4 o;
    o.x = f2b(v.x); o.y = f2b(v.y); o.z = f2b(v.z); o.w = f2b(v.w);
    ((ushort4*)dst)[i] = o;
}

// ---------------------------------------------------------------------------
// prep: gather emb rows (fp32->bf16) -> X + feats; ctx into X; agg into
// feats; h0 init (fp32 + bf16 hi/lo split); zero feats pad rows.
// grid = MPAD blocks x 128 threads.
// ---------------------------------------------------------------------------
__global__ void prep(
    const int* __restrict__ inp,           // [BATCH][S][L] int32
    const float* __restrict__ hidden,      // [S][BATCH][H] fp32
    const float* __restrict__ agg,         // [S][BATCH][H] fp32
    const float* __restrict__ emb,         // [V][E] fp32
    unsigned short* __restrict__ X,        // [S][T*BATCH][KX] bf16
    unsigned short* __restrict__ feats,    // [MPAD][F] bf16
    float* __restrict__ h0,                // [S][H][BATCH] fp32
    unsigned short* __restrict__ hhi0,     // [S][BATCH][H] bf16
    unsigned short* __restrict__ hlo0)
{
    const int r = blockIdx.x;
    const int tid = threadIdx.x; // 128
    if (r >= MROWS) {
        uint2* d = (uint2*)(feats + (size_t)r * F);
        for (int i = tid; i < F / 4; i += 128) d[i] = make_uint2(0u, 0u);
        return;
    }
    const int s = r / (T * BATCH);
    const int rem = r % (T * BATCH);
    const int t = rem >> 4, b = rem & 15;
    const int tok = inp[(b * S + s) * L + t];
    const float4 e = ((const float4*)(emb + (size_t)tok * E))[tid];
    ushort4 eb; eb.x = f2b(e.x); eb.y = f2b(e.y); eb.z = f2b(e.z); eb.w = f2b(e.w);
    ((ushort4*)(X + (size_t)r * KX))[tid] = eb;
    ((ushort4*)(feats + (size_t)r * F))[tid] = eb;
    const float* ctx = (s == 0) ? (agg + (size_t)b * H)
                                : (hidden + (size_t)(s * BATCH + b) * H);
    const float4 c = ((const float4*)ctx)[tid];
    ushort4 cb; cb.x = f2b(c.x); cb.y = f2b(c.y); cb.z = f2b(c.z); cb.w = f2b(c.w);
    ((ushort4*)(X + (size_t)r * KX))[128 + tid] = cb;
    const float4 g = ((const float4*)(agg + (size_t)(s * BATCH + b) * H))[tid];
    ushort4 gb; gb.x = f2b(g.x); gb.y = f2b(g.y); gb.z = f2b(g.z); gb.w = f2b(g.w);
    ((ushort4*)(feats + (size_t)r * F))[256 + tid] = gb;
    if (t == 0) {
        const float* hs = hidden + (size_t)(s * BATCH + b) * H;
#pragma unroll
        for (int jj = 0; jj < 4; ++jj) {
            const int j = tid * 4 + jj;
            const float hv = hs[j];
            h0[(size_t)(s * H + j) * BATCH + b] = hv;
            const unsigned short hb = f2b(hv);
            hhi0[(size_t)(s * BATCH + b) * H + j] = hb;
            hlo0[(size_t)(s * BATCH + b) * H + j] = f2b(hv - b2f(hb));
        }
    }
}

// ---------------------------------------------------------------------------
// gi = X @ W_ih^T + b_ih, per line. Output layout [S][T][G3][BATCH] fp32.
// grid = dim3(6, 23, 4) x 256 thr. wave = 1 Mtile x 4 Ntiles of 16x16.
// ---------------------------------------------------------------------------
__global__ __launch_bounds__(256) void gi_gemm(
    const unsigned short* __restrict__ X,    // [S][T*BATCH][KX] bf16
    const unsigned short* __restrict__ Wih,  // [S][G3][KX] bf16
    const float* __restrict__ bih,           // [S][G3] fp32
    float* __restrict__ gi)                  // [S][T][G3][BATCH]
{
    const int s = blockIdx.z, mt = blockIdx.y;
    const int w = threadIdx.x >> 6, l = threadIdx.x & 63;
    const int lm = l & 15, lq = l >> 4;
    const int nb = blockIdx.x * 256 + w * 64;
    const unsigned short* Arow = X + ((size_t)(s * T * BATCH + mt * 16 + lm)) * KX;
    f32x4 acc[4] = {};
#pragma unroll 4
    for (int k0 = 0; k0 < KX; k0 += 32) {
        bf16x8 a = ldb8(Arow + k0 + lq * 8);
#pragma unroll
        for (int n = 0; n < 4; ++n) {
            const unsigned short* Brow =
                Wih + ((size_t)(s * G3 + nb + n * 16 + lm)) * KX + k0 + lq * 8;
            acc[n] = mfma16(a, ldb8(Brow), acc[n]);
        }
    }
#pragma unroll
    for (int n = 0; n < 4; ++n) {
        const int g = nb + n * 16 + lm;
        const float bias = bih[s * G3 + g];
        f32x4 v;
#pragma unroll
        for (int r = 0; r < 4; ++r) v[r] = acc[n][r] + bias;
        *(f32x4*)&gi[((size_t)((s * T + mt) * G3 + g)) * BATCH + lq * 4] = v;
    }
}

// ---------------------------------------------------------------------------
// One GRU step: gh = [h_hi + h_lo] @ W_hh^T (+ b_hh), gates fused, h_new out.
// Wave handles 16 j-columns for all 16 batch rows of one line; computes the
// matched r/z/n gh tiles itself so no cross-wave exchange is needed.
// grid = 32 blocks x 256 thr (wave = (s, jtile)).
// ---------------------------------------------------------------------------
__global__ __launch_bounds__(256) void gru_step(
    const unsigned short* __restrict__ Whh,    // [S][G3][H] bf16
    const float* __restrict__ bhh,             // [S][G3] fp32
    const float* __restrict__ gi,              // [S][T][G3][BATCH]
    const unsigned short* __restrict__ hhi_in, // [S][BATCH][H] bf16
    const unsigned short* __restrict__ hlo_in, // [S][BATCH][H] bf16
    const float* __restrict__ hin,             // [S][H][BATCH] fp32
    unsigned short* __restrict__ hhi_out,
    unsigned short* __restrict__ hlo_out,
    float* __restrict__ hout,
    unsigned short* __restrict__ feats,        // [MPAD][F] bf16
    int t)
{
    const int w = threadIdx.x >> 6, l = threadIdx.x & 63;
    const int s = blockIdx.x >> 3;
    const int jt = (blockIdx.x & 7) * 4 + w;
    const int j0 = jt * 16;
    const int lm = l & 15, lq = l >> 4;
    f32x4 acc[3] = {};
    const unsigned short* Ahi = hhi_in + ((size_t)(s * BATCH + lm)) * H;
    const unsigned short* Alo = hlo_in + ((size_t)(s * BATCH + lm)) * H;
#pragma unroll 4
    for (int k0 = 0; k0 < H; k0 += 32) {
        bf16x8 ahi = ldb8(Ahi + k0 + lq * 8);
        bf16x8 alo = ldb8(Alo + k0 + lq * 8);
#pragma unroll
        for (int gct = 0; gct < 3; ++gct) {
            bf16x8 bw = ldb8(Whh + ((size_t)(s * G3 + gct * H + j0 + lm)) * H + k0 + lq * 8);
            acc[gct] = mfma16(ahi, bw, acc[gct]);
            acc[gct] = mfma16(alo, bw, acc[gct]);
        }
    }
    const int j = j0 + lm;
    const float br_ = bhh[s * G3 + j];
    const float bz_ = bhh[s * G3 + H + j];
    const float bn_ = bhh[s * G3 + 2 * H + j];
    const size_t gibase = ((size_t)((s * T + t) * G3)) * BATCH;
    const f32x4 gir = *(const f32x4*)&gi[gibase + (size_t)j * BATCH + lq * 4];
    const f32x4 giz = *(const f32x4*)&gi[gibase + (size_t)(H + j) * BATCH + lq * 4];
    const f32x4 gin = *(const f32x4*)&gi[gibase + (size_t)(2 * H + j) * BATCH + lq * 4];
    const f32x4 hold = *(const f32x4*)&hin[(size_t)(s * H + j) * BATCH + lq * 4];
    f32x4 hnew;
#pragma unroll
    for (int r = 0; r < 4; ++r) {
        float rr = sigmoidf_(gir[r] + acc[0][r] + br_);
        float zz = sigmoidf_(giz[r] + acc[1][r] + bz_);
        float nn = tanh_fast(gin[r] + rr * (acc[2][r] + bn_));
        hnew[r] = (1.0f - zz) * nn + zz * hold[r];
    }
    *(f32x4*)&hout[(size_t)(s * H + j) * BATCH + lq * 4] = hnew;
#pragma unroll
    for (int r = 0; r < 4; ++r) {
        const int b = lq * 4 + r;
        const unsigned short hb = f2b(hnew[r]);
        hhi_out[((size_t)(s * BATCH + b)) * H + j] = hb;
        hlo_out[((size_t)(s * BATCH + b)) * H + j] = f2b(hnew[r] - b2f(hb));
        feats[((size_t)(s * T * BATCH + t * 16 + b)) * F + E + j] = hb;
    }
}

// ---------------------------------------------------------------------------
// out[b][s][0][v] = (v==1) ? 1 : 0   (fp32)
// ---------------------------------------------------------------------------
__global__ void first_fill(float* __restrict__ out)
{
    const int row = blockIdx.y; // b*S+s in [0,64)
    const int v0 = (blockIdx.x * blockDim.x + threadIdx.x) * 4;
    if (v0 >= V) return;
    float4 val = make_float4(0.f, 0.f, 0.f, 0.f);
    if (v0 == 0) val.y = 1.0f;
    *(float4*)(out + (size_t)row * L * V + v0) = val;
}

// ---------------------------------------------------------------------------
// logits = feats @ fc_W^T + fc_b, scattered to out[b][s][t+1][v] (fp32).
// m97-style: 128x128 tile, BK=32, global_load_lds width 16, 4 waves, each
// 64x64 via 4x4 of 16x16x32 MFMA. grid = dim3(250, 12) x 256 thr.
// ---------------------------------------------------------------------------
__global__ __launch_bounds__(256) void fc_gemm(
    const unsigned short* __restrict__ feats, // [MPAD][F] bf16
    const unsigned short* __restrict__ fcW,   // [V][F] bf16
    const float* __restrict__ fcb,            // [V] fp32
    float* __restrict__ out)                  // [BATCH][S][L][V] fp32
{
    __shared__ unsigned short As[128 * 32];
    __shared__ unsigned short Bs[128 * 32];
    const int nt = blockIdx.x, mt = blockIdx.y;
    const int tid = threadIdx.x;
    const int w = tid >> 6, l = tid & 63;
    const int wr = w >> 1, wc = w & 1;
    const int lm = l & 15, lq = l >> 4;
    const unsigned short* Abase = feats + (size_t)(mt * 128) * F;
    const unsigned short* Bbase = fcW + (size_t)(nt * 128) * F;

    f32x4 acc[4][4] = {};

    for (int k0 = 0; k0 < F; k0 += 32) {
        __syncthreads();
#pragma unroll
        for (int i = 0; i < 2; ++i) {
            const int idx = i * 256 + tid;
            const int m = idx >> 2, kq = idx & 3;
            gld16(Abase + (size_t)m * F + k0 + kq * 8, &As[(size_t)(i * 256 + w * 64) * 8]);
            gld16(Bbase + (size_t)m * F + k0 + kq * 8, &Bs[(size_t)(i * 256 + w * 64) * 8]);
        }
        __syncthreads();
        bf16x8 af[4], bfr[4];
#pragma unroll
        for (int a = 0; a < 4; ++a) af[a] = ldb8(&As[(wr * 64 + a * 16 + lm) * 32 + lq * 8]);
#pragma unroll
        for (int b = 0; b < 4; ++b) bfr[b] = ldb8(&Bs[(wc * 64 + b * 16 + lm) * 32 + lq * 8]);
#pragma unroll
        for (int a = 0; a < 4; ++a)
#pragma unroll
            for (int b = 0; b < 4; ++b)
                acc[a][b] = mfma16(af[a], bfr[b], acc[a][b]);
    }

#pragma unroll
    for (int b = 0; b < 4; ++b) {
        const int col = nt * 128 + wc * 64 + b * 16 + lm;
        const float bias = fcb[col];
#pragma unroll
        for (int a = 0; a < 4; ++a) {
            const int mbase = mt * 128 + wr * 64 + a * 16 + lq * 4;
#pragma unroll
            for (int r = 0; r < 4; ++r) {
                const int m = mbase + r;
                if (m < MROWS) {
                    const int s = m / (T * BATCH);
                    const int rem = m % (T * BATCH);
                    const int t = rem >> 4, bb = rem & 15;
                    const size_t oidx = ((size_t)((bb * S + s) * L + (t + 1))) * V + col;
                    out[oidx] = acc[a][b][r] + bias;
                }
            }
        }
    }
}

// ---------------------------------------------------------------------------
extern "C" void kernel_launch(void* const* d_in, const int* in_sizes, int n_in,
                              void* d_out, int out_size, void* d_ws, size_t ws_size,
                              hipStream_t stream)
{
    const int* inp       = (const int*)d_in[0];
    const float* hidden  = (const float*)d_in[1];
    const float* agg     = (const float*)d_in[2];
    const float* emb     = (const float*)d_in[3];
    const float* Wih     = (const float*)d_in[4];
    const float* Whh     = (const float*)d_in[5];
    const float* bih     = (const float*)d_in[6];
    const float* bhh     = (const float*)d_in[7];
    const float* fcW     = (const float*)d_in[8];
    const float* fcb     = (const float*)d_in[9];
    float* out           = (float*)d_out;

    char* wsb = (char*)d_ws;
    unsigned short* X      = (unsigned short*)(wsb + 0);             // 3,014,656 B
    float* gi              = (float*)(wsb + 3014656);                // 9,043,968 B
    unsigned short* feats  = (unsigned short*)(wsb + 12058624);      // 4,718,592 B
    float* hb0             = (float*)(wsb + 16777216);               // 131,072 B
    float* hb1             = (float*)(wsb + 16908288);
    unsigned short* hh0    = (unsigned short*)(wsb + 17039360);      // 65,536 B
    unsigned short* hh1    = (unsigned short*)(wsb + 17104896);
    unsigned short* hl0    = (unsigned short*)(wsb + 17170432);
    unsigned short* hl1    = (unsigned short*)(wsb + 17235968);
    unsigned short* Wih_bf = (unsigned short*)(wsb + 17301504);      // 12,582,912 B
    unsigned short* Whh_bf = (unsigned short*)(wsb + 29884416);      //  6,291,456 B
    unsigned short* fcW_bf = (unsigned short*)(wsb + 36175872);      // 98,304,000 B
                                                                     // total 134,479,872 B

    // one-shot weight conversions fp32 -> bf16
    {
        const int n4w = S * G3 * KX / 4;   // 1,572,864
        f32_to_bf16<<<(n4w + 255) / 256, 256, 0, stream>>>(Wih, Wih_bf, n4w);
        const int n4h = S * G3 * H / 4;    //   786,432
        f32_to_bf16<<<(n4h + 255) / 256, 256, 0, stream>>>(Whh, Whh_bf, n4h);
        const int n4f = V * F / 4;         // 12,288,000
        f32_to_bf16<<<(n4f + 255) / 256, 256, 0, stream>>>(fcW, fcW_bf, n4f);
    }

    prep<<<MPAD, 128, 0, stream>>>(inp, hidden, agg, emb, X, feats, hb0, hh0, hl0);
    gi_gemm<<<dim3(6, T, S), 256, 0, stream>>>(X, Wih_bf, bih, gi);

    float* hb[2] = { hb0, hb1 };
    unsigned short* hh[2] = { hh0, hh1 };
    unsigned short* hl[2] = { hl0, hl1 };
    for (int t = 0; t < T; ++t) {
        const int a = t & 1, b = 1 - a;
        gru_step<<<32, 256, 0, stream>>>(Whh_bf, bhh, gi, hh[a], hl[a], hb[a],
                                         hh[b], hl[b], hb[b], feats, t);
    }

    first_fill<<<dim3((V / 4 + 255) / 256, 64), 256, 0, stream>>>(out);
    fc_gemm<<<dim3(V / 128, MPAD / 128), 256, 0, stream>>>(feats, fcW_bf, fcb, out);
}